// Round 10
// baseline (193.417 us; speedup 1.0000x reference)
//
#include <hip/hip_runtime.h>

#define NB     8192
#define HDIM   64
#define SEQ    180
#define MT     16     // batch rows per chain
#define NC     2      // chains per block, HALF-STEP STAGGERED
#define SB     72     // bf16 LDS row stride: 144 B, 16B-aligned
#define XSP    100    // xs prologue row stride (floats)

typedef __bf16 bf16x8 __attribute__((ext_vector_type(8)));
typedef __bf16 bf16x4 __attribute__((ext_vector_type(4)));
typedef float  f32x4  __attribute__((ext_vector_type(4)));

#define L2E 1.44269504088896340736f

__device__ __forceinline__ float tanh_f(float x) {
    float e = __builtin_amdgcn_exp2f((2.0f * L2E) * x);
    return 1.0f - 2.0f * __builtin_amdgcn_rcpf(1.0f + e);
}

#define MFMA __builtin_amdgcn_mfma_f32_16x16x32_bf16

// In-loop barrier: LDS-only drain (vmcnt-free: head stores float across).
#define BAR_LDS() asm volatile("s_waitcnt lgkmcnt(0)\n\ts_barrier" ::: "memory")

// Fused epilogue, op-order IDENTICAL to R18/R22 (bit-reproducible):
// h' = [h*(eN+1) + eZ*(eN-1)] / [(eN+1)(1+eZ)], 5 trans, one ds_write_b64.
__device__ __forceinline__ f32x4 epi_write(f32x4 aR, f32x4 aZ, f32x4 aN,
        f32x4 cR4, f32x4 cZ4, f32x4 bn4, f32x4 cN4, f32x4 one4,
        f32x4 hprev, __bf16* Nh, int wboff) {
    f32x4 tRv = aR * (-L2E) + cR4;
    f32x4 tZv = aZ * (-L2E) + cZ4;
    f32x4 eR, eZ;
#pragma unroll
    for (int r = 0; r < 4; ++r) {
        eR[r] = __builtin_amdgcn_exp2f(tRv[r]);
        eZ[r] = __builtin_amdgcn_exp2f(tZv[r]);
    }
    f32x4 A = eR + one4;
    f32x4 rg;
#pragma unroll
    for (int r = 0; r < 4; ++r) rg[r] = __builtin_amdgcn_rcpf(A[r]);
    f32x4 mm = aN + bn4;
    f32x4 tN = (rg * mm) * (2.0f * L2E) + cN4;
    f32x4 eN;
#pragma unroll
    for (int r = 0; r < 4; ++r) eN[r] = __builtin_amdgcn_exp2f(tN[r]);
    f32x4 wz = eZ + one4;
    f32x4 pz = eZ + hprev;
    f32x4 qz = hprev - eZ;
    f32x4 Ns = eN * pz + qz;
    f32x4 Ds = eN * wz + wz;
    f32x4 rD;
#pragma unroll
    for (int r = 0; r < 4; ++r) rD[r] = __builtin_amdgcn_rcpf(Ds[r]);
    f32x4 hn = Ns * rD;              // exact fp32 carry
    bf16x4 hp;
#pragma unroll
    for (int r = 0; r < 4; ++r) hp[r] = (__bf16)hn[r];
    *(bf16x4*)(Nh + wboff) = hp;
    return hn;
}

// R23 = R22 (dual-chain, 1 block/CU, interleaved math) + HALF-STEP STAGGER:
// each chain gets its OWN publish barrier, alternating. Every inter-barrier
// region pairs chain X's memory/matrix phase (ds_read, head, 6 gate MFMAs)
// with chain Y's pure-register trans epilogue + ds_write -- mutually
// independent, so X's lgkm wait / MFMA latency / barrier convergence hide
// under Y's ~350cy of epilogue issue. R22 measured: issue-packing works
// (817cy ~= predicted 870) but 696cy stall remained because both chains hit
// the sync phase TOGETHER; this de-phases them structurally. Gate
// accumulators (12 VGPR/chain) carry across one barrier. 2 barriers/step but
// each converges identical streams. Math per chain op-identical to R18/R22.
// (resubmit: fixed NB macro collision with a local variable name)
__global__ __launch_bounds__(256) void gru_all(
        const float* __restrict__ z, const int* __restrict__ labels,
        const float* __restrict__ embed_w, const float* __restrict__ fc_w,
        const float* __restrict__ fc_b, const float* __restrict__ w_hh,
        const float* __restrict__ b_ih, const float* __restrict__ b_hh,
        const float* __restrict__ out_w, const float* __restrict__ out_b,
        float* __restrict__ out) {
    __shared__ __align__(16) __bf16 hbuf[NC][2][MT * SB];  // [chain][buf]
    __shared__ __align__(16) float  xs[NC * MT * XSP];     // h0 input [z|embed]

    const int t = threadIdx.x;
    const int w = t >> 6;          // wave 0..3
    const int l = t & 63;
    const int q = l >> 4;          // quad 0..3
    const int n16 = l & 15;
    const int jg = 16 * w + n16;   // W row this lane loads (A-frag m-index)
    const int jb = 16 * w + 4 * q; // first of the 4 h-cols this lane epilogues
    const int bbase = blockIdx.x * (NC * MT);

    // ---- prologue A: stage x = [z, embed(labels)] for 32 rows into LDS ----
    for (int c = t; c < NC * MT * 24; c += 256) {   // 24 f32x4 chunks per row
        int m = c / 24, kk = (c % 24) * 4;
        f32x4 v;
        if (kk < 32) v = *(const f32x4*)(z + (size_t)(bbase + m) * 32 + kk);
        else         v = *(const f32x4*)(embed_w + labels[bbase + m] * 64 + (kk - 32));
        *(f32x4*)(xs + m * XSP + kk) = v;
    }

    // ---- persistent w_hh fragments, plain bf16 (MFMA A-operands) ----
    bf16x8 whi[3][2];
#pragma unroll
    for (int g = 0; g < 3; ++g) {
        const float* pr = w_hh + (g * 64 + jg) * HDIM;
#pragma unroll
        for (int ks = 0; ks < 2; ++ks) {
            const float* p = pr + ks * 32 + q * 8;
            f32x4 va = *(const f32x4*)(p);
            f32x4 vb = *(const f32x4*)(p + 4);
#pragma unroll
            for (int j2 = 0; j2 < 4; ++j2) {
                whi[g][ks][j2]     = (__bf16)va[j2];
                whi[g][ks][4 + j2] = (__bf16)vb[j2];
            }
        }
    }

    // ---- output-head A fragments ----
    bf16x8 obhi[2];
#pragma unroll
    for (int ks = 0; ks < 2; ++ks) {
        f32x4 va = {0.f, 0.f, 0.f, 0.f}, vb = {0.f, 0.f, 0.f, 0.f};
        if (n16 < 2) {
            va = *(const f32x4*)(out_w + n16 * 64 + ks * 32 + q * 8);
            vb = *(const f32x4*)(out_w + n16 * 64 + ks * 32 + q * 8 + 4);
        }
#pragma unroll
        for (int j2 = 0; j2 < 4; ++j2) {
            obhi[ks][j2]     = (__bf16)va[j2];
            obhi[ks][4 + j2] = (__bf16)vb[j2];
        }
    }
    const f32x4 obias = (q == 0) ? f32x4{out_b[0], out_b[1], 0.f, 0.f}
                                 : f32x4{0.f, 0.f, 0.f, 0.f};
    const f32x4 kZ = {0.f, 0.f, 0.f, 0.f};
    const f32x4 one4 = {1.f, 1.f, 1.f, 1.f};

    const bool ostorer = (q == 0) && ((n16 >> 2) == w);

    // per-lane gate constants (chain-shared)
    const f32x4 bihR = *(const f32x4*)(b_ih + jb);
    const f32x4 bhhR = *(const f32x4*)(b_hh + jb);
    const f32x4 bihZ = *(const f32x4*)(b_ih + 64 + jb);
    const f32x4 bhhZ = *(const f32x4*)(b_hh + 64 + jb);
    const f32x4 cR4 = (bihR + bhhR) * (-L2E);
    const f32x4 cZ4 = (bihZ + bhhZ) * (-L2E);
    const f32x4 bn4 = *(const f32x4*)(b_hh + 128 + jb);
    const f32x4 cN4 = (*(const f32x4*)(b_ih + 128 + jb)) * (2.0f * L2E);

    const int rdoff = n16 * SB + q * 8;
    const int wboff = n16 * SB + jb;
    float* opbA = out + (size_t)(bbase + n16) * (SEQ * 2);
    float* opbB = out + (size_t)(bbase + MT + n16) * (SEQ * 2);

    __syncthreads();   // xs ready

    // ---- prologue B: h0 for BOTH chains (fc_w row loads shared) ----
    f32x4 hpA, hpB;
    {
        f32x4 aA = *(const f32x4*)(fc_b + jb);
        f32x4 aB = aA;
        for (int kc = 0; kc < 24; ++kc) {
            f32x4 xvA = *(const f32x4*)(xs + n16 * XSP + kc * 4);
            f32x4 xvB = *(const f32x4*)(xs + (MT + n16) * XSP + kc * 4);
#pragma unroll
            for (int r = 0; r < 4; ++r) {
                f32x4 wv = *(const f32x4*)(fc_w + (size_t)(jb + r) * 96 + kc * 4);
                aA[r] += wv[0] * xvA[0] + wv[1] * xvA[1] + wv[2] * xvA[2] + wv[3] * xvA[3];
                aB[r] += wv[0] * xvB[0] + wv[1] * xvB[1] + wv[2] * xvB[2] + wv[3] * xvB[3];
            }
        }
        bf16x4 ha, hb;
#pragma unroll
        for (int r = 0; r < 4; ++r) {
            hpA[r] = tanh_f(aA[r]); ha[r] = (__bf16)hpA[r];
            hpB[r] = tanh_f(aB[r]); hb[r] = (__bf16)hpB[r];
        }
        *(bf16x4*)(hbuf[0][0] + wboff) = ha;
        *(bf16x4*)(hbuf[1][0] + wboff) = hb;
    }
    __syncthreads();   // A_0, B_0 published

    // ---- stagger prologue: pre-compute chain B's gate MFMAs for step 0 ----
    bf16x8 paA0 = {}, paA1 = {};
    bf16x8 paB0, paB1;
    f32x4 aRA, aZA, aNA, aRB, aZB, aNB;
    {
        const __bf16* HB = hbuf[1][0];
        paB0 = *(const bf16x8*)(HB + rdoff);
        paB1 = *(const bf16x8*)(HB + rdoff + 32);
        aRB = MFMA(whi[0][0], paB0, kZ, 0, 0, 0);
        aZB = MFMA(whi[1][0], paB0, kZ, 0, 0, 0);
        aNB = MFMA(whi[2][0], paB0, kZ, 0, 0, 0);
        aRB = MFMA(whi[0][1], paB1, aRB, 0, 0, 0);
        aZB = MFMA(whi[1][1], paB1, aZB, 0, 0, 0);
        aNB = MFMA(whi[2][1], paB1, aNB, 0, 0, 0);
    }

    // ---- main loop: 2 staggered regions per step, 1 barrier each ----
    for (int tt = 0; tt < SEQ / 2; ++tt) {
#pragma unroll
        for (int par = 0; par < 2; ++par) {
            const int ts = 2 * tt + par;   // time-step; ts&1 == par

            // ===== EVEN region: A memory/matrix phase || B epilogue =====
            {
                const __bf16* HA = hbuf[0][par];       // A_ts
                __bf16*      nbp = hbuf[1][par ^ 1];   // B_{ts+1} dest
                bf16x8 a0 = *(const bf16x8*)(HA + rdoff);
                bf16x8 a1 = *(const bf16x8*)(HA + rdoff + 32);

                // deferred head A (paA = A_{ts-1} -> out row ts-2)
                {
                    f32x4 o = obias;
                    o = MFMA(obhi[0], paA0, o, 0, 0, 0);
                    o = MFMA(obhi[1], paA1, o, 0, 0, 0);
                    if (ts >= 2 && ostorer)
                        *(float2*)(opbA + (ts - 2) * 2) = make_float2(o[0], o[1]);
                }

                // gate MFMAs A_ts (results consumed NEXT region)
                f32x4 nR = MFMA(whi[0][0], a0, kZ, 0, 0, 0);
                f32x4 nZ = MFMA(whi[1][0], a0, kZ, 0, 0, 0);
                f32x4 nN = MFMA(whi[2][0], a0, kZ, 0, 0, 0);
                nR = MFMA(whi[0][1], a1, nR, 0, 0, 0);
                nZ = MFMA(whi[1][1], a1, nZ, 0, 0, 0);
                nN = MFMA(whi[2][1], a1, nN, 0, 0, 0);

                // epilogue B (register-only; hides A's lgkm/MFMA latency)
                hpB = epi_write(aRB, aZB, aNB, cR4, cZ4, bn4, cN4, one4,
                                hpB, nbp, wboff);

                aRA = nR; aZA = nZ; aNA = nN;
                paA0 = a0; paA1 = a1;
                BAR_LDS();   // publishes B_{ts+1}
            }

            // ===== ODD region: B memory/matrix phase || A epilogue =====
            {
                const __bf16* HB = hbuf[1][par ^ 1];   // B_{ts+1}
                __bf16*      nap = hbuf[0][par ^ 1];   // A_{ts+1} dest
                bf16x8 c0 = *(const bf16x8*)(HB + rdoff);
                bf16x8 c1 = *(const bf16x8*)(HB + rdoff + 32);

                // deferred head B (paB = B_ts -> out row ts-1)
                {
                    f32x4 o = obias;
                    o = MFMA(obhi[0], paB0, o, 0, 0, 0);
                    o = MFMA(obhi[1], paB1, o, 0, 0, 0);
                    if (ts >= 1 && ostorer)
                        *(float2*)(opbB + (ts - 1) * 2) = make_float2(o[0], o[1]);
                }

                // gate MFMAs B_{ts+1}
                f32x4 nR = MFMA(whi[0][0], c0, kZ, 0, 0, 0);
                f32x4 nZ = MFMA(whi[1][0], c0, kZ, 0, 0, 0);
                f32x4 nN = MFMA(whi[2][0], c0, kZ, 0, 0, 0);
                nR = MFMA(whi[0][1], c1, nR, 0, 0, 0);
                nZ = MFMA(whi[1][1], c1, nZ, 0, 0, 0);
                nN = MFMA(whi[2][1], c1, nN, 0, 0, 0);

                // epilogue A -> h A_{ts+1}
                hpA = epi_write(aRA, aZA, aNA, cR4, cZ4, bn4, cN4, one4,
                                hpA, nap, wboff);

                aRB = nR; aZB = nZ; aNB = nN;
                paB0 = c0; paB1 = c1;
                BAR_LDS();   // publishes A_{ts+1}
            }
        }
    }

    // ---- tail ----
    // A: head(paA=A_179) -> row 178; read A_180 -> head -> row 179.
    // B: rows 0..178 stored in-loop; head(paB=B_180) -> row 179.
    {
        f32x4 oA = obias;
        oA = MFMA(obhi[0], paA0, oA, 0, 0, 0);
        oA = MFMA(obhi[1], paA1, oA, 0, 0, 0);
        f32x4 oB = obias;
        oB = MFMA(obhi[0], paB0, oB, 0, 0, 0);
        oB = MFMA(obhi[1], paB1, oB, 0, 0, 0);
        if (ostorer) {
            *(float2*)(opbA + (SEQ - 2) * 2) = make_float2(oA[0], oA[1]);
            *(float2*)(opbB + (SEQ - 1) * 2) = make_float2(oB[0], oB[1]);
        }
        const __bf16* HA = hbuf[0][0];     // A_180 (180 & 1 == 0)
        bf16x8 a0 = *(const bf16x8*)(HA + rdoff);
        bf16x8 a1 = *(const bf16x8*)(HA + rdoff + 32);
        f32x4 o2 = obias;
        o2 = MFMA(obhi[0], a0, o2, 0, 0, 0);
        o2 = MFMA(obhi[1], a1, o2, 0, 0, 0);
        if (ostorer)
            *(float2*)(opbA + (SEQ - 1) * 2) = make_float2(o2[0], o2[1]);
    }
}

extern "C" void kernel_launch(void* const* d_in, const int* in_sizes, int n_in,
                              void* d_out, int out_size, void* d_ws, size_t ws_size,
                              hipStream_t stream) {
    (void)in_sizes; (void)n_in; (void)out_size; (void)d_ws; (void)ws_size;
    const float* z       = (const float*)d_in[0];
    const int*   labels  = (const int*)d_in[1];
    const float* embed_w = (const float*)d_in[2];
    const float* fc_w    = (const float*)d_in[3];
    const float* fc_b    = (const float*)d_in[4];
    // d_in[5] = w_ih: unused (GRU input is all zeros; b_ih carries the effect)
    const float* w_hh    = (const float*)d_in[6];
    const float* b_ih    = (const float*)d_in[7];
    const float* b_hh    = (const float*)d_in[8];
    const float* out_w   = (const float*)d_in[9];
    const float* out_b   = (const float*)d_in[10];
    float* out = (float*)d_out;

    gru_all<<<NB / (NC * MT), 256, 0, stream>>>(z, labels, embed_w, fc_w, fc_b,
                                                w_hh, b_ih, b_hh, out_w, out_b, out);
}

// Round 11
// 162.067 us; speedup vs baseline: 1.1934x; 1.1934x over previous
//
#include <hip/hip_runtime.h>

#define NB     8192
#define HDIM   64
#define SEQ    180
#define MT     16     // batch rows per block
#define SB     72     // bf16 LDS row stride: 144 B, 16B-aligned (SB=68 regressed: misaligned b128)
#define XSP    100    // xs prologue row stride (floats)

typedef __bf16 bf16x8 __attribute__((ext_vector_type(8)));
typedef __bf16 bf16x4 __attribute__((ext_vector_type(4)));
typedef float  f32x4  __attribute__((ext_vector_type(4)));

#define L2E 1.44269504088896340736f

__device__ __forceinline__ float tanh_f(float x) {
    float e = __builtin_amdgcn_exp2f((2.0f * L2E) * x);
    return 1.0f - 2.0f * __builtin_amdgcn_rcpf(1.0f + e);
}

#define MFMA __builtin_amdgcn_mfma_f32_16x16x32_bf16

// In-loop barrier: LDS-only drain (R17: neutral vs __syncthreads; kept so the
// deferred head's global store floats across barriers).
#define BAR_LDS() asm volatile("s_waitcnt lgkmcnt(0)\n\ts_barrier" ::: "memory")

// R24 = R20 (best, 106us) + REGISTER-NEUTRAL constant folding:
//  - R,Z w_hh rows pre-scaled by -L2E before bf16 cast; their first MFMA is
//    C-seeded with cR4/cZ4 (same registers, moved from epilogue FMA to C
//    operand). tR/tZ FMAs die; exp2 reads the accumulator directly (-8 instr,
//    one trans-chain level shorter).
//  - N gate C-seeded with bn4 (already live; N weights NOT scaled, cN4
//    unchanged). mm=aN+bn4 dies (-4 instr).
//  Net -12 VALU instr/wave-step, ZERO new live constants -> VGPR stays ~120.
// R21 proved this fold numerically (passed, absmax bit-identical); it
// regressed only because its N-path variant added registers (cNb+cN4) and
// crossed the 128-VGPR occupancy cliff (120->132, occupancy halved).
// Structure lessons now closed: R16/R22 dual-chain (issue-2x / in-phase
// stall), R19 MT=8 (tile-fixed instr count), R20 setprio/sleep (phase lock
// benign), R23 split barriers (convergence cost > overlap gain). 2 blocks/CU
// + 1 barrier/step + issue-shaving is the operating point.
__global__ __launch_bounds__(256) void gru_all(
        const float* __restrict__ z, const int* __restrict__ labels,
        const float* __restrict__ embed_w, const float* __restrict__ fc_w,
        const float* __restrict__ fc_b, const float* __restrict__ w_hh,
        const float* __restrict__ b_ih, const float* __restrict__ b_hh,
        const float* __restrict__ out_w, const float* __restrict__ out_b,
        float* __restrict__ out) {
    __shared__ __align__(16) __bf16 hbuf[2][MT * SB];  // [buf] bf16(h)
    __shared__ __align__(16) float  xs[MT * XSP];      // h0 input [z|embed]

    const int t = threadIdx.x;
    const int w = t >> 6;          // wave 0..3
    const int l = t & 63;
    const int q = l >> 4;          // quad 0..3
    const int n16 = l & 15;
    const int jg = 16 * w + n16;   // W row this lane loads (A-frag m-index)
    const int jb = 16 * w + 4 * q; // first of the 4 h-cols this lane epilogues
    const int bbase = blockIdx.x * MT;

    // ---- prologue A: stage x = [z, embed(labels)] for 16 rows into LDS ----
    for (int c = t; c < MT * 24; c += 256) {    // 24 f32x4 chunks per row
        int m = c / 24, kk = (c % 24) * 4;
        f32x4 v;
        if (kk < 32) v = *(const f32x4*)(z + (size_t)(bbase + m) * 32 + kk);
        else         v = *(const f32x4*)(embed_w + labels[bbase + m] * 64 + (kk - 32));
        *(f32x4*)(xs + m * XSP + kk) = v;
    }

    // ---- persistent w_hh fragments: R,Z pre-scaled by -L2E; N plain ----
    // A[m = n16][k = q*8+j + 32ks] = scale[g] * w_hh[g*64 + jg][k]
    bf16x8 whi[3][2];
#pragma unroll
    for (int g = 0; g < 3; ++g) {
        const float wsc = (g == 2) ? 1.0f : (-L2E);
        const float* pr = w_hh + (g * 64 + jg) * HDIM;
#pragma unroll
        for (int ks = 0; ks < 2; ++ks) {
            const float* p = pr + ks * 32 + q * 8;
            f32x4 va = *(const f32x4*)(p);
            f32x4 vb = *(const f32x4*)(p + 4);
#pragma unroll
            for (int j2 = 0; j2 < 4; ++j2) {
                whi[g][ks][j2]     = (__bf16)(va[j2] * wsc);
                whi[g][ks][4 + j2] = (__bf16)(vb[j2] * wsc);
            }
        }
    }

    // ---- output-head A fragments: A[m=n16][k] = out_w[n16][k] (n16<2 live) --
    bf16x8 obhi[2];
#pragma unroll
    for (int ks = 0; ks < 2; ++ks) {
        f32x4 va = {0.f, 0.f, 0.f, 0.f}, vb = {0.f, 0.f, 0.f, 0.f};
        if (n16 < 2) {
            va = *(const f32x4*)(out_w + n16 * 64 + ks * 32 + q * 8);
            vb = *(const f32x4*)(out_w + n16 * 64 + ks * 32 + q * 8 + 4);
        }
#pragma unroll
        for (int j2 = 0; j2 < 4; ++j2) {
            obhi[ks][j2]     = (__bf16)va[j2];
            obhi[ks][4 + j2] = (__bf16)vb[j2];
        }
    }
    // C/D bias by m-row (out-col): live rows m=0,1 sit at q==0, reg r=0,1
    const f32x4 obias = (q == 0) ? f32x4{out_b[0], out_b[1], 0.f, 0.f}
                                 : f32x4{0.f, 0.f, 0.f, 0.f};
    const f32x4 one4 = {1.f, 1.f, 1.f, 1.f};

    // every wave stores output for its 4 rows: q==0 lane, rows 4w..4w+3
    const bool ostorer = (q == 0) && ((n16 >> 2) == w);

    // per-lane gate constants: vectors over the lane's 4 cols jb..jb+3.
    // cR4/cZ4/bn4 are now MFMA C-seeds (C reg r <-> gate col jb+r, proven R21).
    const f32x4 bihR = *(const f32x4*)(b_ih + jb);
    const f32x4 bhhR = *(const f32x4*)(b_hh + jb);
    const f32x4 bihZ = *(const f32x4*)(b_ih + 64 + jb);
    const f32x4 bhhZ = *(const f32x4*)(b_hh + 64 + jb);
    const f32x4 cR4 = (bihR + bhhR) * (-L2E);
    const f32x4 cZ4 = (bihZ + bhhZ) * (-L2E);
    const f32x4 bn4 = *(const f32x4*)(b_hh + 128 + jb);
    const f32x4 cN4 = (*(const f32x4*)(b_ih + 128 + jb)) * (2.0f * L2E);

    const int rdoff = n16 * SB + q * 8;    // h B-frag offset (16B-aligned)
    const int wboff = n16 * SB + jb;       // state-write offset (8B-aligned)
    float* opb = out + (size_t)(bbase + n16) * (SEQ * 2);  // this lane's row

    __syncthreads();   // xs ready

    // ---- prologue B: h0 = tanh(fc_b + fc_w . x); lane -> row n16, 4 cols ----
    f32x4 hprev;
    {
        f32x4 a = *(const f32x4*)(fc_b + jb);
        for (int kc = 0; kc < 24; ++kc) {
            f32x4 xv = *(const f32x4*)(xs + n16 * XSP + kc * 4);
#pragma unroll
            for (int r = 0; r < 4; ++r) {
                f32x4 wv = *(const f32x4*)(fc_w + (size_t)(jb + r) * 96 + kc * 4);
                a[r] += wv[0] * xv[0] + wv[1] * xv[1] + wv[2] * xv[2] + wv[3] * xv[3];
            }
        }
        bf16x4 hp;
#pragma unroll
        for (int r = 0; r < 4; ++r) {
            hprev[r] = tanh_f(a[r]);
            hp[r] = (__bf16)hprev[r];
        }
        *(bf16x4*)(hbuf[0] + wboff) = hp;   // one ds_write_b64
    }
    __syncthreads();   // state 0 published in buf 0

    // Anti-phase the two co-resident blocks (i and i+256 share a CU).
    if ((blockIdx.x >> 8) & 1) __builtin_amdgcn_s_sleep(11);

    // previous step's b-frags for the deferred head (garbage first 2 iters;
    // computed unconditionally for wave balance, store is predicated)
    bf16x8 pb0 = {}, pb1 = {};

    for (int u = 0; u < SEQ / 4; ++u) {
#pragma unroll
        for (int s = 0; s < 4; ++s) {
            const int p = s & 1;
            const __bf16* Hh = hbuf[p];
            __bf16* Nh = hbuf[1 - p];

            // h B-frags of state i = 4u+s: B[k=q*8+j][n16] = h[n16][k]
            bf16x8 b0 = *(const bf16x8*)(Hh + rdoff);
            bf16x8 b1 = *(const bf16x8*)(Hh + rdoff + 32);

            // deferred output head (state i-1 -> out row i-2): register-only
            // MFMAs fill the ds_read lgkm-wait shadow right after the barrier
            {
                f32x4 o = obias;
                o = MFMA(obhi[0], pb0, o, 0, 0, 0);
                o = MFMA(obhi[1], pb1, o, 0, 0, 0);
                if ((u > 0 || s >= 2) && ostorer)
                    *(float2*)(opb + (8 * u + 2 * s - 4)) = make_float2(o[0], o[1]);
            }

            __builtin_amdgcn_s_setprio(1);

            // gates, bias-seeded: aR = -L2E*(W_R.h + bR_tot),
            // aZ = -L2E*(W_Z.h + bZ_tot), aN = W_N.h + b_hhN
            f32x4 aR, aZ, aN;
            aR = MFMA(whi[0][0], b0, cR4, 0, 0, 0);
            aZ = MFMA(whi[1][0], b0, cZ4, 0, 0, 0);
            aN = MFMA(whi[2][0], b0, bn4, 0, 0, 0);
            aR = MFMA(whi[0][1], b1, aR, 0, 0, 0);
            aZ = MFMA(whi[1][1], b1, aZ, 0, 0, 0);
            aN = MFMA(whi[2][1], b1, aN, 0, 0, 0);

            // fused epilogue: exp2 straight off the R/Z accumulators.
            // h' = [h*(eN+1) + eZ*(eN-1)] / [(eN+1)(1+eZ)]
            f32x4 eR, eZ;
#pragma unroll
            for (int r = 0; r < 4; ++r) {
                eR[r] = __builtin_amdgcn_exp2f(aR[r]);
                eZ[r] = __builtin_amdgcn_exp2f(aZ[r]);
            }
            f32x4 A = eR + one4;
            f32x4 rg;
#pragma unroll
            for (int r = 0; r < 4; ++r) rg[r] = __builtin_amdgcn_rcpf(A[r]);
            f32x4 tN = (rg * aN) * (2.0f * L2E) + cN4;   // aN already has bn4
            f32x4 eN;
#pragma unroll
            for (int r = 0; r < 4; ++r) eN[r] = __builtin_amdgcn_exp2f(tN[r]);
            f32x4 wz = eZ + one4;            // 1 + eZ
            f32x4 pz = eZ + hprev;           // eZ + h
            f32x4 qz = hprev - eZ;           // h - eZ
            f32x4 Nst = eN * pz + qz;        // h*(eN+1) + eZ*(eN-1)
            f32x4 Dst = eN * wz + wz;        // (eN+1)*(1+eZ)
            f32x4 rD;
#pragma unroll
            for (int r = 0; r < 4; ++r) rD[r] = __builtin_amdgcn_rcpf(Dst[r]);
            f32x4 hn = Nst * rD;             // exact fp32 carry
            hprev = hn;
            bf16x4 hp;
#pragma unroll
            for (int r = 0; r < 4; ++r) hp[r] = (__bf16)hn[r];
            *(bf16x4*)(Nh + wboff) = hp;     // one ds_write_b64

            __builtin_amdgcn_s_setprio(0);

            pb0 = b0; pb1 = b1;              // renamed, not copied (unroll 4)

            BAR_LDS();   // state i+1 published (LDS-only drain; stores float)
        }
    }

    // tail: deferred head of state 179 (pb) -> row 178, then state 180 -> 179
    {
        f32x4 o = obias;
        o = MFMA(obhi[0], pb0, o, 0, 0, 0);
        o = MFMA(obhi[1], pb1, o, 0, 0, 0);
        if (ostorer)
            *(float2*)(opb + (SEQ - 2) * 2) = make_float2(o[0], o[1]);

        const __bf16* Hh = hbuf[0];
        bf16x8 b0 = *(const bf16x8*)(Hh + rdoff);
        bf16x8 b1 = *(const bf16x8*)(Hh + rdoff + 32);
        f32x4 o2 = obias;
        o2 = MFMA(obhi[0], b0, o2, 0, 0, 0);
        o2 = MFMA(obhi[1], b1, o2, 0, 0, 0);
        if (ostorer)
            *(float2*)(opb + (SEQ - 1) * 2) = make_float2(o2[0], o2[1]);
    }
}

extern "C" void kernel_launch(void* const* d_in, const int* in_sizes, int n_in,
                              void* d_out, int out_size, void* d_ws, size_t ws_size,
                              hipStream_t stream) {
    (void)in_sizes; (void)n_in; (void)out_size; (void)d_ws; (void)ws_size;
    const float* z       = (const float*)d_in[0];
    const int*   labels  = (const int*)d_in[1];
    const float* embed_w = (const float*)d_in[2];
    const float* fc_w    = (const float*)d_in[3];
    const float* fc_b    = (const float*)d_in[4];
    // d_in[5] = w_ih: unused (GRU input is all zeros; b_ih carries the effect)
    const float* w_hh    = (const float*)d_in[6];
    const float* b_ih    = (const float*)d_in[7];
    const float* b_hh    = (const float*)d_in[8];
    const float* out_w   = (const float*)d_in[9];
    const float* out_b   = (const float*)d_in[10];
    float* out = (float*)d_out;

    gru_all<<<NB / MT, 256, 0, stream>>>(z, labels, embed_w, fc_w, fc_b,
                                         w_hh, b_ih, b_hh, out_w, out_b, out);
}

// Round 12
// 157.951 us; speedup vs baseline: 1.2245x; 1.0261x over previous
//
#include <hip/hip_runtime.h>

#define NB     8192
#define HDIM   64
#define SEQ    180
#define MT     16     // batch rows per block
#define SB     72     // bf16 LDS row stride: 144 B, 16B-aligned (SB=68 regressed: misaligned b128)
#define XSP    100    // xs prologue row stride (floats)

typedef __bf16 bf16x8 __attribute__((ext_vector_type(8)));
typedef __bf16 bf16x4 __attribute__((ext_vector_type(4)));
typedef float  f32x4  __attribute__((ext_vector_type(4)));

#define L2E 1.44269504088896340736f

__device__ __forceinline__ float tanh_f(float x) {
    float e = __builtin_amdgcn_exp2f((2.0f * L2E) * x);
    return 1.0f - 2.0f * __builtin_amdgcn_rcpf(1.0f + e);
}

#define MFMA __builtin_amdgcn_mfma_f32_16x16x32_bf16

// In-loop barrier: LDS-only drain (R17: neutral vs __syncthreads; kept so the
// deferred head's global store floats across barriers).
#define BAR_LDS() asm volatile("s_waitcnt lgkmcnt(0)\n\ts_barrier" ::: "memory")

// R25 = R24 (best, 101us: R/Z fold into MFMA A/C operands, deferred head,
// fused 5-trans epilogue, 2 blocks/CU) + STATIC ASYMMETRIC WAVE PRIORITY:
// one block of each co-resident pair holds s_setprio(1) permanently; in-loop
// toggles removed (they reset static prio; R20 proved toggling neutral).
// Rationale: per-wave issue 371cy, serial chain ~380cy -> ideal anti-phase
// period ~900-1000cy, measured 1349 -> ~400cy of coverable stall remains.
// All prior phase tools were SYMMETRIC (one-shot sleep decays; toggled prio
// is a no-op when both blocks hit prio-1 together) -- coupled identical
// oscillators re-lock. A permanent priority difference is self-consistent:
// arbitration always favors one block, the other fills its stall windows.
// Math untouched -> absmax must stay 0.00390625.
// Closed branches: R16/R22 dual-chain, R19 MT=8, R21/N-fold (=132 VGPR
// cliff), R23 split barriers. VGPR must stay <=128.
__global__ __launch_bounds__(256) void gru_all(
        const float* __restrict__ z, const int* __restrict__ labels,
        const float* __restrict__ embed_w, const float* __restrict__ fc_w,
        const float* __restrict__ fc_b, const float* __restrict__ w_hh,
        const float* __restrict__ b_ih, const float* __restrict__ b_hh,
        const float* __restrict__ out_w, const float* __restrict__ out_b,
        float* __restrict__ out) {
    __shared__ __align__(16) __bf16 hbuf[2][MT * SB];  // [buf] bf16(h)
    __shared__ __align__(16) float  xs[MT * XSP];      // h0 input [z|embed]

    const int t = threadIdx.x;
    const int w = t >> 6;          // wave 0..3
    const int l = t & 63;
    const int q = l >> 4;          // quad 0..3
    const int n16 = l & 15;
    const int jg = 16 * w + n16;   // W row this lane loads (A-frag m-index)
    const int jb = 16 * w + 4 * q; // first of the 4 h-cols this lane epilogues
    const int bbase = blockIdx.x * MT;

    // ---- prologue A: stage x = [z, embed(labels)] for 16 rows into LDS ----
    for (int c = t; c < MT * 24; c += 256) {    // 24 f32x4 chunks per row
        int m = c / 24, kk = (c % 24) * 4;
        f32x4 v;
        if (kk < 32) v = *(const f32x4*)(z + (size_t)(bbase + m) * 32 + kk);
        else         v = *(const f32x4*)(embed_w + labels[bbase + m] * 64 + (kk - 32));
        *(f32x4*)(xs + m * XSP + kk) = v;
    }

    // ---- persistent w_hh fragments: R,Z pre-scaled by -L2E; N plain ----
    // A[m = n16][k = q*8+j + 32ks] = scale[g] * w_hh[g*64 + jg][k]
    bf16x8 whi[3][2];
#pragma unroll
    for (int g = 0; g < 3; ++g) {
        const float wsc = (g == 2) ? 1.0f : (-L2E);
        const float* pr = w_hh + (g * 64 + jg) * HDIM;
#pragma unroll
        for (int ks = 0; ks < 2; ++ks) {
            const float* p = pr + ks * 32 + q * 8;
            f32x4 va = *(const f32x4*)(p);
            f32x4 vb = *(const f32x4*)(p + 4);
#pragma unroll
            for (int j2 = 0; j2 < 4; ++j2) {
                whi[g][ks][j2]     = (__bf16)(va[j2] * wsc);
                whi[g][ks][4 + j2] = (__bf16)(vb[j2] * wsc);
            }
        }
    }

    // ---- output-head A fragments: A[m=n16][k] = out_w[n16][k] (n16<2 live) --
    bf16x8 obhi[2];
#pragma unroll
    for (int ks = 0; ks < 2; ++ks) {
        f32x4 va = {0.f, 0.f, 0.f, 0.f}, vb = {0.f, 0.f, 0.f, 0.f};
        if (n16 < 2) {
            va = *(const f32x4*)(out_w + n16 * 64 + ks * 32 + q * 8);
            vb = *(const f32x4*)(out_w + n16 * 64 + ks * 32 + q * 8 + 4);
        }
#pragma unroll
        for (int j2 = 0; j2 < 4; ++j2) {
            obhi[ks][j2]     = (__bf16)va[j2];
            obhi[ks][4 + j2] = (__bf16)vb[j2];
        }
    }
    // C/D bias by m-row (out-col): live rows m=0,1 sit at q==0, reg r=0,1
    const f32x4 obias = (q == 0) ? f32x4{out_b[0], out_b[1], 0.f, 0.f}
                                 : f32x4{0.f, 0.f, 0.f, 0.f};
    const f32x4 one4 = {1.f, 1.f, 1.f, 1.f};

    // every wave stores output for its 4 rows: q==0 lane, rows 4w..4w+3
    const bool ostorer = (q == 0) && ((n16 >> 2) == w);

    // per-lane gate constants: vectors over the lane's 4 cols jb..jb+3.
    // cR4/cZ4/bn4 are MFMA C-seeds (C reg r <-> gate col jb+r, proven R21/R24).
    const f32x4 bihR = *(const f32x4*)(b_ih + jb);
    const f32x4 bhhR = *(const f32x4*)(b_hh + jb);
    const f32x4 bihZ = *(const f32x4*)(b_ih + 64 + jb);
    const f32x4 bhhZ = *(const f32x4*)(b_hh + 64 + jb);
    const f32x4 cR4 = (bihR + bhhR) * (-L2E);
    const f32x4 cZ4 = (bihZ + bhhZ) * (-L2E);
    const f32x4 bn4 = *(const f32x4*)(b_hh + 128 + jb);
    const f32x4 cN4 = (*(const f32x4*)(b_ih + 128 + jb)) * (2.0f * L2E);

    const int rdoff = n16 * SB + q * 8;    // h B-frag offset (16B-aligned)
    const int wboff = n16 * SB + jb;       // state-write offset (8B-aligned)
    float* opb = out + (size_t)(bbase + n16) * (SEQ * 2);  // this lane's row

    __syncthreads();   // xs ready

    // ---- prologue B: h0 = tanh(fc_b + fc_w . x); lane -> row n16, 4 cols ----
    f32x4 hprev;
    {
        f32x4 a = *(const f32x4*)(fc_b + jb);
        for (int kc = 0; kc < 24; ++kc) {
            f32x4 xv = *(const f32x4*)(xs + n16 * XSP + kc * 4);
#pragma unroll
            for (int r = 0; r < 4; ++r) {
                f32x4 wv = *(const f32x4*)(fc_w + (size_t)(jb + r) * 96 + kc * 4);
                a[r] += wv[0] * xv[0] + wv[1] * xv[1] + wv[2] * xv[2] + wv[3] * xv[3];
            }
        }
        bf16x4 hp;
#pragma unroll
        for (int r = 0; r < 4; ++r) {
            hprev[r] = tanh_f(a[r]);
            hp[r] = (__bf16)hprev[r];
        }
        *(bf16x4*)(hbuf[0] + wboff) = hp;   // one ds_write_b64
    }
    __syncthreads();   // state 0 published in buf 0

    // STATIC asymmetric priority between the two co-resident blocks
    // (i and i+256 share a CU): one block holds prio 1 for the whole loop.
    // Plus the half-period sleep seed. Symmetric tools (one-shot sleep alone,
    // toggled setprio) all re-locked; a permanent asymmetry cannot.
    if ((blockIdx.x >> 8) & 1) {
        __builtin_amdgcn_s_setprio(1);
        __builtin_amdgcn_s_sleep(11);
    }

    // previous step's b-frags for the deferred head (garbage first 2 iters;
    // computed unconditionally for wave balance, store is predicated)
    bf16x8 pb0 = {}, pb1 = {};

    for (int u = 0; u < SEQ / 4; ++u) {
#pragma unroll
        for (int s = 0; s < 4; ++s) {
            const int p = s & 1;
            const __bf16* Hh = hbuf[p];
            __bf16* Nh = hbuf[1 - p];

            // h B-frags of state i = 4u+s: B[k=q*8+j][n16] = h[n16][k]
            bf16x8 b0 = *(const bf16x8*)(Hh + rdoff);
            bf16x8 b1 = *(const bf16x8*)(Hh + rdoff + 32);

            // deferred output head (state i-1 -> out row i-2): register-only
            // MFMAs fill the ds_read lgkm-wait shadow right after the barrier
            {
                f32x4 o = obias;
                o = MFMA(obhi[0], pb0, o, 0, 0, 0);
                o = MFMA(obhi[1], pb1, o, 0, 0, 0);
                if ((u > 0 || s >= 2) && ostorer)
                    *(float2*)(opb + (8 * u + 2 * s - 4)) = make_float2(o[0], o[1]);
            }

            // gates, bias-seeded: aR = -L2E*(W_R.h + bR_tot),
            // aZ = -L2E*(W_Z.h + bZ_tot), aN = W_N.h + b_hhN
            f32x4 aR, aZ, aN;
            aR = MFMA(whi[0][0], b0, cR4, 0, 0, 0);
            aZ = MFMA(whi[1][0], b0, cZ4, 0, 0, 0);
            aN = MFMA(whi[2][0], b0, bn4, 0, 0, 0);
            aR = MFMA(whi[0][1], b1, aR, 0, 0, 0);
            aZ = MFMA(whi[1][1], b1, aZ, 0, 0, 0);
            aN = MFMA(whi[2][1], b1, aN, 0, 0, 0);

            // fused epilogue: exp2 straight off the R/Z accumulators.
            // h' = [h*(eN+1) + eZ*(eN-1)] / [(eN+1)(1+eZ)]
            f32x4 eR, eZ;
#pragma unroll
            for (int r = 0; r < 4; ++r) {
                eR[r] = __builtin_amdgcn_exp2f(aR[r]);
                eZ[r] = __builtin_amdgcn_exp2f(aZ[r]);
            }
            f32x4 A = eR + one4;
            f32x4 rg;
#pragma unroll
            for (int r = 0; r < 4; ++r) rg[r] = __builtin_amdgcn_rcpf(A[r]);
            f32x4 tN = (rg * aN) * (2.0f * L2E) + cN4;   // aN already has bn4
            f32x4 eN;
#pragma unroll
            for (int r = 0; r < 4; ++r) eN[r] = __builtin_amdgcn_exp2f(tN[r]);
            f32x4 wz = eZ + one4;            // 1 + eZ
            f32x4 pz = eZ + hprev;           // eZ + h
            f32x4 qz = hprev - eZ;           // h - eZ
            f32x4 Nst = eN * pz + qz;        // h*(eN+1) + eZ*(eN-1)
            f32x4 Dst = eN * wz + wz;        // (eN+1)*(1+eZ)
            f32x4 rD;
#pragma unroll
            for (int r = 0; r < 4; ++r) rD[r] = __builtin_amdgcn_rcpf(Dst[r]);
            f32x4 hn = Nst * rD;             // exact fp32 carry
            hprev = hn;
            bf16x4 hp;
#pragma unroll
            for (int r = 0; r < 4; ++r) hp[r] = (__bf16)hn[r];
            *(bf16x4*)(Nh + wboff) = hp;     // one ds_write_b64

            pb0 = b0; pb1 = b1;              // renamed, not copied (unroll 4)

            BAR_LDS();   // state i+1 published (LDS-only drain; stores float)
        }
    }

    // tail: deferred head of state 179 (pb) -> row 178, then state 180 -> 179
    {
        f32x4 o = obias;
        o = MFMA(obhi[0], pb0, o, 0, 0, 0);
        o = MFMA(obhi[1], pb1, o, 0, 0, 0);
        if (ostorer)
            *(float2*)(opb + (SEQ - 2) * 2) = make_float2(o[0], o[1]);

        const __bf16* Hh = hbuf[0];
        bf16x8 b0 = *(const bf16x8*)(Hh + rdoff);
        bf16x8 b1 = *(const bf16x8*)(Hh + rdoff + 32);
        f32x4 o2 = obias;
        o2 = MFMA(obhi[0], b0, o2, 0, 0, 0);
        o2 = MFMA(obhi[1], b1, o2, 0, 0, 0);
        if (ostorer)
            *(float2*)(opb + (SEQ - 1) * 2) = make_float2(o2[0], o2[1]);
    }
}

extern "C" void kernel_launch(void* const* d_in, const int* in_sizes, int n_in,
                              void* d_out, int out_size, void* d_ws, size_t ws_size,
                              hipStream_t stream) {
    (void)in_sizes; (void)n_in; (void)out_size; (void)d_ws; (void)ws_size;
    const float* z       = (const float*)d_in[0];
    const int*   labels  = (const int*)d_in[1];
    const float* embed_w = (const float*)d_in[2];
    const float* fc_w    = (const float*)d_in[3];
    const float* fc_b    = (const float*)d_in[4];
    // d_in[5] = w_ih: unused (GRU input is all zeros; b_ih carries the effect)
    const float* w_hh    = (const float*)d_in[6];
    const float* b_ih    = (const float*)d_in[7];
    const float* b_hh    = (const float*)d_in[8];
    const float* out_w   = (const float*)d_in[9];
    const float* out_b   = (const float*)d_in[10];
    float* out = (float*)d_out;

    gru_all<<<NB / MT, 256, 0, stream>>>(z, labels, embed_w, fc_w, fc_b,
                                         w_hh, b_ih, b_hh, out_w, out_b, out);
}